// Round 17
// baseline (245.327 us; speedup 1.0000x reference)
//
#include <hip/hip_runtime.h>
#include <hip/hip_bf16.h>
#include <cstdint>

// ---- problem constants ----
#define BB 32
#define NN 1024
#define CC 768
#define MM 64
#define HH 12
#define DD 64

typedef float f4v __attribute__((ext_vector_type(4)));
typedef __bf16 bf8 __attribute__((ext_vector_type(8)));
typedef __bf16 bf4 __attribute__((ext_vector_type(4)));

__device__ __forceinline__ f4v mfma16(bf8 a, bf8 b, f4v c) {
    return __builtin_amdgcn_mfma_f32_16x16x32_bf16(a, b, c, 0, 0, 0);
}
__device__ __forceinline__ __bf16 f2bf(float f) { return (__bf16)f; }

__device__ __forceinline__ void gl2lds16(const void* g, void* lds) {
    __builtin_amdgcn_global_load_lds((const __attribute__((address_space(1))) void*)g,
                                     (__attribute__((address_space(3))) void*)lds, 16, 0, 0);
}

// ================= fragment-linear layout (lane-order) =================
// frag[tile16][kc32][lane64][8]: element (row, k) at
//   tile = row>>4, kc = k>>5, LANE = ((k>>3)&3)*16 + (row&15), e = k&7
// A wave's fragment load = base + l*8 -> one coalesced 1KB line; lane l gets
// exactly its MFMA fragment element (row = l&15, k = (l>>4)*8+e).
// Used for: xb, Wc/Wq/Wp, q, o, kf, vf, c_bmn, xt.

// ---------- all weights fp32 -> bf16; Wc/Wq/Wp FRAG-LINEAR, Wk/Wv row-major ----------
__global__ __launch_bounds__(256) void k_cvtW(
        const float* __restrict__ Wc, const float* __restrict__ Wq,
        const float* __restrict__ Wk, const float* __restrict__ Wv,
        const float* __restrict__ Wp,
        __bf16* __restrict__ wc, __bf16* __restrict__ wq,
        __bf16* __restrict__ wk, __bf16* __restrict__ wv,
        __bf16* __restrict__ wp) {
    const float* in; __bf16* out; int n4; int frag;
    switch (blockIdx.y) {
        case 0: in = Wc; out = wc; n4 = MM * CC / 4; frag = 1; break;
        case 1: in = Wq; out = wq; n4 = CC * CC / 4; frag = 1; break;
        case 2: in = Wk; out = wk; n4 = CC * CC / 4; frag = 0; break;
        case 3: in = Wv; out = wv; n4 = CC * CC / 4; frag = 0; break;
        default: in = Wp; out = wp; n4 = CC * CC / 4; frag = 1; break;
    }
    int i = blockIdx.x * 256 + threadIdx.x;
    if (i < n4) {
        float4 v = *(const float4*)&in[i * 4];
        bf4 o; o[0] = f2bf(v.x); o[1] = f2bf(v.y); o[2] = f2bf(v.z); o[3] = f2bf(v.w);
        if (frag) {
            int lin = i * 4, m = lin / CC, c = lin % CC;
            size_t off = ((size_t)((m >> 4) * 24 + (c >> 5))) * 512
                       + ((((c >> 3) & 3) * 16) + (m & 15)) * 8 + (c & 7);
            *(bf4*)&out[off] = o;
        } else {
            *(bf4*)&out[i * 4] = o;
        }
    }
}

// ---------- K0 (R15-verified): x -> xb FRAG-LINEAR  AND  xt FRAG-LINEAR-TRANSPOSED ----------
__global__ __launch_bounds__(256) void k_cvtx(const float* __restrict__ x,
        __bf16* __restrict__ xb, __bf16* __restrict__ xt) {
    int c0 = blockIdx.x * 64, n0 = blockIdx.y * 64, b = blockIdx.z;
    __shared__ __align__(16) __bf16 tileT[64 * 66];
    __shared__ __align__(16) __bf16 tileR[64 * 72];
    int t = threadIdx.x;
#pragma unroll
    for (int i = 0; i < 4; i++) {
        int idx = t + 256 * i, r = idx >> 4, cq = idx & 15;
        float4 v = *(const float4*)&x[((size_t)(b * NN + n0 + r)) * CC + c0 + cq * 4];
        float vv[4] = {v.x, v.y, v.z, v.w};
        bf4 o;
#pragma unroll
        for (int j = 0; j < 4; j++) {
            __bf16 bv = f2bf(vv[j]);
            o[j] = bv;
            tileT[(cq * 4 + j) * 66 + r] = bv;
        }
        *(bf4*)&tileR[r * 72 + cq * 4] = o;
    }
    __syncthreads();
    int gnt = b * 64 + (n0 >> 4);
    int kc0 = c0 >> 5;
    int lane = t & 63;
#pragma unroll
    for (int i = 0; i < 2; i++) {
        int idx = t + 256 * i;
        int nt_loc = idx >> 7, kc_loc = (idx >> 6) & 1;
        int row = nt_loc * 16 + (lane & 15);
        int col = kc_loc * 32 + (lane >> 4) * 8;
        bf8 v = *(const bf8*)&tileR[row * 72 + col];
        *(bf8*)&xb[((size_t)((gnt + nt_loc) * 24 + kc0 + kc_loc)) * 512 + lane * 8] = v;
    }
#pragma unroll
    for (int i = 0; i < 2; i++) {
        int idx = t + 256 * i;
        int bid = idx >> 6, lane2 = idx & 63;
        int ct_loc = bid >> 1, nc_loc = bid & 1;
        bf8 v2 = *(const bf8*)&tileT[(ct_loc * 16 + (lane2 & 15)) * 66 + nc_loc * 32 + (lane2 >> 4) * 8];
        *(bf8*)&xt[((size_t)((b * 48 + (c0 >> 4) + ct_loc) * 32 + (n0 >> 5) + nc_loc)) * 512 + lane2 * 8] = v2;
    }
}

// ---------- K1 (R15-verified): c_bmn = sigmoid(x@Wc^T + bc)/N -> FRAG-LINEAR cf ----------
__global__ __launch_bounds__(256) void k_cluster(const __bf16* __restrict__ xb,
        const __bf16* __restrict__ Wc, const float* __restrict__ bc,
        __bf16* __restrict__ cbmn) {
    int n0 = blockIdx.x * 128, b = blockIdx.y;
    __shared__ __align__(16) __bf16 ctile[64 * 136];
    int t = threadIdx.x, w = t >> 6, l = t & 63, quad = (l >> 4), l16 = l & 15;
    int nt0 = b * 64 + (n0 >> 4);
    f4v acc[2][4];
#pragma unroll
    for (int i = 0; i < 2; i++) for (int j = 0; j < 4; j++) acc[i][j] = (f4v)0.0f;
    for (int kc = 0; kc < 24; kc++) {
        bf8 afr[2], bfr[4];
#pragma unroll
        for (int sr = 0; sr < 2; sr++)
            afr[sr] = *(const bf8*)&xb[((size_t)((nt0 + w * 2 + sr) * 24 + kc)) * 512 + l * 8];
#pragma unroll
        for (int sc = 0; sc < 4; sc++)
            bfr[sc] = *(const bf8*)&Wc[((size_t)(sc * 24 + kc)) * 512 + l * 8];
#pragma unroll
        for (int sr = 0; sr < 2; sr++)
#pragma unroll
            for (int sc = 0; sc < 4; sc++)
                acc[sr][sc] = mfma16(afr[sr], bfr[sc], acc[sr][sc]);
    }
#pragma unroll
    for (int sr = 0; sr < 2; sr++)
#pragma unroll
        for (int sc = 0; sc < 4; sc++) {
            int m = sc * 16 + l16;
            float bias = bc[m];
#pragma unroll
            for (int r = 0; r < 4; r++) {
                float val = acc[sr][sc][r] + bias;
                val = 1.0f / (1.0f + __expf(-val));
                int nloc = w * 32 + sr * 16 + quad * 4 + r;
                ctile[m * 136 + nloc] = f2bf(val * (1.0f / 1024.0f));
            }
        }
    __syncthreads();
#pragma unroll
    for (int i = 0; i < 4; i++) {
        int idx = t + 256 * i, bid = idx >> 6, lane = idx & 63;
        int mt = bid >> 2, ncl = bid & 3;
        bf8 v = *(const bf8*)&ctile[(mt * 16 + (lane & 15)) * 136 + ncl * 32 + (lane >> 4) * 8];
        *(bf8*)&cbmn[((size_t)((b * 4 + mt) * 32 + (n0 >> 5) + ncl)) * 512 + lane * 8] = v;
    }
}

// ---------- K2 (R15-verified): z = sum_n cf * xtf ----------
__global__ __launch_bounds__(256) void k_z(const __bf16* __restrict__ cbmn,
        const __bf16* __restrict__ xt, float* __restrict__ z) {
    int c0 = blockIdx.x * 64, b = blockIdx.y;
    int t = threadIdx.x, w = t >> 6, l = t & 63, quad = l >> 4, l16 = l & 15;
    f4v acc[4];
#pragma unroll
    for (int j = 0; j < 4; j++) acc[j] = (f4v)0.0f;
    for (int nc = 0; nc < 32; nc++) {
        bf8 afr = *(const bf8*)&cbmn[((size_t)((b * 4 + w) * 32 + nc)) * 512 + l * 8];
#pragma unroll
        for (int sc = 0; sc < 4; sc++) {
            bf8 bfr = *(const bf8*)&xt[((size_t)((b * 48 + (c0 >> 4) + sc) * 32 + nc)) * 512 + l * 8];
            acc[sc] = mfma16(afr, bfr, acc[sc]);
        }
    }
#pragma unroll
    for (int sc = 0; sc < 4; sc++) {
        int cc = c0 + sc * 16 + l16;
#pragma unroll
        for (int r = 0; r < 4; r++) {
            int m = w * 16 + quad * 4 + r;
            z[((size_t)(b * MM + m)) * CC + cc] = acc[sc][r];
        }
    }
}

// ---------- K2b: L2-normalize rows of z, write bf16 (unchanged) ----------
__global__ __launch_bounds__(256) void k_znorm(const float* __restrict__ z, __bf16* __restrict__ zb) {
    int w = threadIdx.x >> 6, l = threadIdx.x & 63;
    int row = blockIdx.x * 4 + w;
    const float* zr = &z[(size_t)row * CC];
    float v[12]; float ss = 0.f;
#pragma unroll
    for (int i = 0; i < 12; i++) { v[i] = zr[l + i * 64]; ss += v[i] * v[i]; }
#pragma unroll
    for (int off = 32; off; off >>= 1) ss += __shfl_xor(ss, off);
    float s = 1.0f / fmaxf(sqrtf(ss), 1e-12f);
    __bf16* zo = &zb[(size_t)row * CC];
#pragma unroll
    for (int i = 0; i < 12; i++) zo[l + i * 64] = f2bf(v[i] * s);
}

// ---------- K3 (R14-verified): k/v projections -> FRAG-LINEAR kf/vf ----------
__global__ __launch_bounds__(256) void k_kv(const __bf16* __restrict__ zb,
        const __bf16* __restrict__ Wk, const float* __restrict__ bk,
        const __bf16* __restrict__ Wv, const float* __restrict__ bv,
        __bf16* __restrict__ kout, __bf16* __restrict__ vtout) {
    int ct = blockIdx.x, b = blockIdx.y, which = blockIdx.z;
    const __bf16* W = which ? Wv : Wk;
    const float* bias = which ? bv : bk;
    __shared__ __align__(16) __bf16 tile[128 * 72];
    int t = threadIdx.x, w = t >> 6, l = t & 63, quad = l >> 4, l16 = l & 15;
    int h0 = ct * 2;
    f4v acc[4][2];
#pragma unroll
    for (int i = 0; i < 4; i++) for (int j = 0; j < 2; j++) acc[i][j] = (f4v)0.0f;
    for (int k0 = 0; k0 < CC; k0 += 32) {
        bf8 afr[4], bfr[2];
#pragma unroll
        for (int sr = 0; sr < 4; sr++)
            afr[sr] = *(const bf8*)&zb[((size_t)(b * MM + sr * 16 + l16)) * CC + k0 + quad * 8];
#pragma unroll
        for (int sc = 0; sc < 2; sc++)
            bfr[sc] = *(const bf8*)&W[((size_t)(ct * 128 + w * 32 + sc * 16 + l16)) * CC + k0 + quad * 8];
#pragma unroll
        for (int sr = 0; sr < 4; sr++)
#pragma unroll
            for (int sc = 0; sc < 2; sc++)
                acc[sr][sc] = mfma16(afr[sr], bfr[sc], acc[sr][sc]);
    }
#pragma unroll
    for (int sr = 0; sr < 4; sr++)
#pragma unroll
        for (int sc = 0; sc < 2; sc++) {
            int col = w * 32 + sc * 16 + l16;
            float bb = bias[ct * 128 + col];
#pragma unroll
            for (int r = 0; r < 4; r++) {
                int m = sr * 16 + quad * 4 + r;
                __bf16 val = f2bf(acc[sr][sc][r] + bb);
                if (which == 0) tile[m * 136 + col] = val;
                else            tile[col * 72 + m] = val;
            }
        }
    __syncthreads();
#pragma unroll
    for (int i = 0; i < 4; i++) {
        int idx = t + 256 * i;
        int bid = idx >> 6, lane = idx & 63;
        int h_loc = bid >> 3, t4 = (bid >> 1) & 3, kc2 = bid & 1;
        int h = h0 + h_loc;
        if (which == 0) {
            int m = t4 * 16 + (lane & 15), d = kc2 * 32 + (lane >> 4) * 8;
            bf8 v = *(const bf8*)&tile[m * 136 + h_loc * 64 + d];
            *(bf8*)&kout[((size_t)(((b * HH + h) * 4 + t4) * 2 + kc2)) * 512 + lane * 8] = v;
        } else {
            int d = t4 * 16 + (lane & 15), m = kc2 * 32 + (lane >> 4) * 8;
            bf8 v = *(const bf8*)&tile[(h_loc * 64 + d) * 72 + m];
            *(bf8*)&vtout[((size_t)(((b * HH + h) * 4 + t4) * 2 + kc2)) * 512 + lane * 8] = v;
        }
    }
}

// ======== HYBRID 128x64 GEMM, 4 waves in 2x2 grid, per-wave 64x32 ========
// R17: one more step on the verified occupancy axis (R16: 2->3 blocks/CU won).
// acc[4][2]=32 + bcur/bnxt=32 + afr=16 + addr ~20 => ~100 regs << 128 budget
// at launch_bounds(256,4) -> 4 blocks/CU, 16 waves/CU, spill-safe margin.
// Same verified skeleton: A staged depth-3 (24 KB), B reg-double-buffered,
// counted vmcnt re-derived for 2 B-loads/iter (outstanding 6 -> vmcnt(4)).
#define STAGE_AF(Asrc, buf, kcs)                                                      \
    do {                                                                              \
        __bf16* _d = (buf);                                                           \
        gl2lds16(&(Asrc)[((size_t)((gt0 + w) * 24 + (kcs))) * 512 + l * 8], &_d[w * 512]); \
        gl2lds16(&(Asrc)[((size_t)((gt0 + w + 4) * 24 + (kcs))) * 512 + l * 8], &_d[(w + 4) * 512]); \
    } while (0)

#define GEMM_KLOOP_T(Asrc, Bsrc)                                                      \
    bf8 bcur[2], bnxt[2];                                                             \
    _Pragma("unroll")                                                                 \
    for (int sc = 0; sc < 2; sc++)                                                    \
        bcur[sc] = *(const bf8*)&(Bsrc)[((size_t)((jt * 4 + wn * 2 + sc) * 24)) * 512 + l * 8]; \
    STAGE_AF(Asrc, As3, 0);                                                           \
    STAGE_AF(Asrc, As3 + 4096, 1);                                                    \
    asm volatile("s_waitcnt vmcnt(2)" ::: "memory");                                  \
    __builtin_amdgcn_s_barrier();                                                     \
    for (int kt = 0; kt < 24; ++kt) {                                                 \
        const __bf16* As = As3 + (kt % 3) * 4096;                                     \
        if (kt < 23) {                                                                \
            _Pragma("unroll")                                                         \
            for (int sc = 0; sc < 2; sc++)                                            \
                bnxt[sc] = *(const bf8*)&(Bsrc)[((size_t)((jt * 4 + wn * 2 + sc) * 24 + kt + 1)) * 512 + l * 8]; \
        }                                                                             \
        bf8 afr[4];                                                                   \
        _Pragma("unroll")                                                             \
        for (int sr = 0; sr < 4; sr++)                                                \
            afr[sr] = *(const bf8*)&As[(wm * 4 + sr) * 512 + l * 8];                  \
        __builtin_amdgcn_sched_barrier(0);                                            \
        if (kt < 22) STAGE_AF(Asrc, As3 + ((kt + 2) % 3) * 4096, kt + 2);             \
        __builtin_amdgcn_s_setprio(1);                                                \
        _Pragma("unroll")                                                             \
        for (int sr = 0; sr < 4; sr++)                                                \
            _Pragma("unroll")                                                         \
            for (int sc = 0; sc < 2; sc++)                                            \
                acc[sr][sc] = mfma16(afr[sr], bcur[sc], acc[sr][sc]);                 \
        __builtin_amdgcn_s_setprio(0);                                                \
        if (kt < 23) {                                                                \
            _Pragma("unroll")                                                         \
            for (int sc = 0; sc < 2; sc++) bcur[sc] = bnxt[sc];                       \
        }                                                                             \
        if (kt < 22)       asm volatile("s_waitcnt vmcnt(4)" ::: "memory");           \
        else if (kt == 22) asm volatile("s_waitcnt vmcnt(2)" ::: "memory");           \
        __builtin_amdgcn_s_barrier();                                                 \
    }

// ---------- K4: q = xb @ Wq^T + bq -> q FRAG-LINEAR [nt][h][kcs][lane][8] ----------
__global__ __launch_bounds__(256, 4) void k_qproj(const __bf16* __restrict__ xb,
        const __bf16* __restrict__ Wq, const float* __restrict__ bq,
        __bf16* __restrict__ qb) {
    // 3072 blocks = 8 XCD x 384 (32 row-stripes x 12 jt per chunk); jt == head.
    int orig = blockIdx.x;
    int lid = (orig & 7) * 384 + (orig >> 3);
    int jt = lid % 12;
    int gt0 = (lid / 12) * 8;   // 8 row-tiles = 128 rows

    __shared__ __align__(16) __bf16 As3[3 * 4096];  // 24 KB; epilogue (18 KB) aliases it
    int t = threadIdx.x, w = t >> 6, l = t & 63, quad = l >> 4, l16 = l & 15;
    int wm = w >> 1, wn = w & 1;   // 2x2 wave grid; per-wave 64 rows x 32 cols
    f4v acc[4][2];
#pragma unroll
    for (int i = 0; i < 4; i++) for (int j = 0; j < 2; j++) acc[i][j] = (f4v)0.0f;

    GEMM_KLOOP_T(xb, Wq);

    // epilogue: all 4 waves dump their disjoint 64x32 regions into eb[128][72]
    // in ONE phase, barrier, then frag-linear 1KB-line stores for head h = jt.
    __bf16* eb = As3;
#pragma unroll
    for (int sc = 0; sc < 2; sc++) {
        int col = jt * 64 + wn * 32 + sc * 16 + l16;
        float bb = bq[col];
#pragma unroll
        for (int sr = 0; sr < 4; sr++)
#pragma unroll
            for (int r = 0; r < 4; r++)
                eb[(wm * 64 + sr * 16 + quad * 4 + r) * 72 + wn * 32 + sc * 16 + l16] = f2bf(acc[sr][sc][r] + bb);
    }
    __syncthreads();
#pragma unroll
    for (int i = 0; i < 4; i++) {
        int idx = t + 256 * i, nt = idx >> 7, kcs = (idx >> 6) & 1, lane = idx & 63;
        bf8 v = *(const bf8*)&eb[(nt * 16 + (lane & 15)) * 72 + kcs * 32 + (lane >> 4) * 8];
        *(bf8*)&qb[((size_t)(((gt0 + nt) * 12 + jt) * 2 + kcs)) * 512 + lane * 8] = v;
    }
}

// ---------- K5 (R15-verified): attention (q, kf, vf all frag-linear) ----------
#define QS 72
__global__ __launch_bounds__(256) void k_attn(const __bf16* __restrict__ qb,
        const __bf16* __restrict__ kb, const __bf16* __restrict__ vt,
        __bf16* __restrict__ ob) {
    int n0 = blockIdx.x * 128, h = blockIdx.y, b = blockIdx.z;
    __shared__ __align__(16) __bf16 ps[128 * QS];
    int t = threadIdx.x, w = t >> 6, l = t & 63, quad = l >> 4, l16 = l & 15;
    size_t bh = (size_t)(b * HH + h);
    int nt0 = b * 64 + (n0 >> 4);

    f4v sacc[2][4];
#pragma unroll
    for (int i = 0; i < 2; i++) for (int j = 0; j < 4; j++) sacc[i][j] = (f4v)0.0f;
#pragma unroll
    for (int kc = 0; kc < 2; kc++) {
        bf8 afr[2], bfr[4];
#pragma unroll
        for (int sr = 0; sr < 2; sr++)
            afr[sr] = *(const bf8*)&qb[((size_t)(((nt0 + w * 2 + sr) * 12 + h) * 2 + kc)) * 512 + l * 8];
#pragma unroll
        for (int sc = 0; sc < 4; sc++)
            bfr[sc] = *(const bf8*)&kb[((size_t)((bh * 4 + sc) * 2 + kc)) * 512 + l * 8];
#pragma unroll
        for (int sr = 0; sr < 2; sr++)
#pragma unroll
            for (int sc = 0; sc < 4; sc++)
                sacc[sr][sc] = mfma16(afr[sr], bfr[sc], sacc[sr][sc]);
    }
#pragma unroll
    for (int sr = 0; sr < 2; sr++) {
#pragma unroll
        for (int r = 0; r < 4; r++) {
            float mx = -1e30f;
#pragma unroll
            for (int sc = 0; sc < 4; sc++) mx = fmaxf(mx, sacc[sr][sc][r] * 0.125f);
#pragma unroll
            for (int off = 1; off < 16; off <<= 1) mx = fmaxf(mx, __shfl_xor(mx, off));
            float e[4]; float sum = 0.f;
#pragma unroll
            for (int sc = 0; sc < 4; sc++) { e[sc] = __expf(sacc[sr][sc][r] * 0.125f - mx); sum += e[sc]; }
#pragma unroll
            for (int off = 1; off < 16; off <<= 1) sum += __shfl_xor(sum, off);
            float inv = 1.0f / sum;
            int row = w * 32 + sr * 16 + quad * 4 + r;
#pragma unroll
            for (int sc = 0; sc < 4; sc++) ps[row * QS + sc * 16 + l16] = f2bf(e[sc] * inv);
        }
    }
    f4v oacc[2][4];
#pragma unroll
    for (int i = 0; i < 2; i++) for (int j = 0; j < 4; j++) oacc[i][j] = (f4v)0.0f;
#pragma unroll
    for (int kc = 0; kc < 2; kc++) {
        bf8 afr[2], bfr[4];
#pragma unroll
        for (int sr = 0; sr < 2; sr++)
            afr[sr] = *(const bf8*)&ps[(w * 32 + sr * 16 + l16) * QS + kc * 32 + quad * 8];
#pragma unroll
        for (int sc = 0; sc < 4; sc++)
            bfr[sc] = *(const bf8*)&vt[((size_t)((bh * 4 + sc) * 2 + kc)) * 512 + l * 8];
#pragma unroll
        for (int sr = 0; sr < 2; sr++)
#pragma unroll
            for (int sc = 0; sc < 4; sc++)
                oacc[sr][sc] = mfma16(afr[sr], bfr[sc], oacc[sr][sc]);
    }
#pragma unroll
    for (int sr = 0; sr < 2; sr++)
#pragma unroll
        for (int sc = 0; sc < 4; sc++) {
            int row = w * 32 + sr * 16;
#pragma unroll
            for (int r = 0; r < 4; r++)
                ps[(row + quad * 4 + r) * QS + sc * 16 + l16] = f2bf(oacc[sr][sc][r]);
        }
    __syncthreads();
#pragma unroll
    for (int i = 0; i < 4; i++) {
        int idx = t + 256 * i, nt = idx >> 7, kcs = (idx >> 6) & 1, lane = idx & 63;
        bf8 v = *(const bf8*)&ps[(nt * 16 + (lane & 15)) * QS + kcs * 32 + (lane >> 4) * 8];
        *(bf8*)&ob[((size_t)((nt0 + nt) * 24 + h * 2 + kcs)) * 512 + lane * 8] = v;
    }
}

// ---------- K6: out = o @ Wp^T + bp  (o frag-linear in, fp32 row-major out) ----------
__global__ __launch_bounds__(256, 4) void k_oproj(const __bf16* __restrict__ ob,
        const __bf16* __restrict__ Wp, const float* __restrict__ bp,
        float* __restrict__ out) {
    int orig = blockIdx.x;
    int lid = (orig & 7) * 384 + (orig >> 3);
    int jt = lid % 12;
    int gt0 = (lid / 12) * 8;
    size_t arow0 = (size_t)(lid / 12) * 128;

    __shared__ __align__(16) __bf16 As3[3 * 4096];  // 24 KB; fp32 epilogue (17 KB/half) aliases it
    int t = threadIdx.x, w = t >> 6, l = t & 63, quad = l >> 4, l16 = l & 15;
    int wm = w >> 1, wn = w & 1;
    f4v acc[4][2];
#pragma unroll
    for (int i = 0; i < 4; i++) for (int j = 0; j < 2; j++) acc[i][j] = (f4v)0.0f;

    GEMM_KLOOP_T(ob, Wp);

    // epilogue: 2 row-half phases; phase hm: the 2 waves with wm==hm write their
    // 64x32 fp32 regions (pad 68, 17 KB), all threads store full float4 lines.
    float* ebf = (float*)As3;
    for (int hm = 0; hm < 2; ++hm) {
        if (wm == hm) {
#pragma unroll
            for (int sc = 0; sc < 2; sc++) {
                int col = jt * 64 + wn * 32 + sc * 16 + l16;
                float bb = bp[col];
#pragma unroll
                for (int sr = 0; sr < 4; sr++)
#pragma unroll
                    for (int r = 0; r < 4; r++)
                        ebf[(sr * 16 + quad * 4 + r) * 68 + wn * 32 + sc * 16 + l16] = acc[sr][sc][r] + bb;
            }
        }
        __syncthreads();
#pragma unroll
        for (int i = 0; i < 4; i++) {
            int idx = t + 256 * i, row = idx >> 4, c4 = idx & 15;
            *(float4*)&out[(arow0 + hm * 64 + row) * CC + jt * 64 + c4 * 4] =
                *(const float4*)&ebf[row * 68 + c4 * 4];
        }
        __syncthreads();
    }
}

extern "C" void kernel_launch(void* const* d_in, const int* in_sizes, int n_in,
                              void* d_out, int out_size, void* d_ws, size_t ws_size,
                              hipStream_t stream) {
    (void)in_sizes; (void)n_in; (void)out_size; (void)ws_size;
    const float* x  = (const float*)d_in[0];
    const float* Wc = (const float*)d_in[1];
    const float* bc = (const float*)d_in[2];
    const float* Wq = (const float*)d_in[3];
    const float* bq = (const float*)d_in[4];
    const float* Wk = (const float*)d_in[5];
    const float* bk = (const float*)d_in[6];
    const float* Wv = (const float*)d_in[7];
    const float* bv = (const float*)d_in[8];
    const float* Wp = (const float*)d_in[9];
    const float* bp = (const float*)d_in[10];
    float* out = (float*)d_out;

    char* ws = (char*)d_ws;
    size_t off = 0;
    auto alloc = [&](size_t bytes) { void* p = ws + off; off = (off + bytes + 255) & ~(size_t)255; return p; };
    __bf16* wc_b = (__bf16*)alloc((size_t)MM * CC * 2);
    __bf16* wq_b = (__bf16*)alloc((size_t)CC * CC * 2);
    __bf16* wk_b = (__bf16*)alloc((size_t)CC * CC * 2);
    __bf16* wv_b = (__bf16*)alloc((size_t)CC * CC * 2);
    __bf16* wp_b = (__bf16*)alloc((size_t)CC * CC * 2);
    __bf16* xb   = (__bf16*)alloc((size_t)BB * NN * CC * 2);
    __bf16* xt_o = (__bf16*)alloc((size_t)BB * NN * CC * 2);  // xtf, reused as o (frag)
    __bf16* q_b  = (__bf16*)alloc((size_t)BB * NN * CC * 2);
    __bf16* c_bmn= (__bf16*)alloc((size_t)BB * MM * NN * 2);
    float*  z_f  = (float*) alloc((size_t)BB * MM * CC * 4);
    __bf16* z_b  = (__bf16*)alloc((size_t)BB * MM * CC * 2);
    __bf16* k_b  = (__bf16*)alloc((size_t)BB * HH * MM * DD * 2);
    __bf16* v_t  = (__bf16*)alloc((size_t)BB * HH * MM * DD * 2);

    k_cvtW<<<dim3((CC * CC / 4 + 255) / 256, 5), 256, 0, stream>>>(
        Wc, Wq, Wk, Wv, Wp, wc_b, wq_b, wk_b, wv_b, wp_b);

    k_cvtx<<<dim3(CC / 64, NN / 64, BB), 256, 0, stream>>>(x, xb, xt_o);
    k_cluster<<<dim3(NN / 128, BB), 256, 0, stream>>>(xb, wc_b, bc, c_bmn);
    k_z<<<dim3(CC / 64, BB), 256, 0, stream>>>(c_bmn, xt_o, z_f);
    k_znorm<<<(BB * MM) / 4, 256, 0, stream>>>(z_f, z_b);
    k_kv<<<dim3(CC / 128, BB, 2), 256, 0, stream>>>(z_b, wk_b, bk, wv_b, bv, k_b, v_t);
    k_qproj<<<dim3((BB * NN / 128) * 12), 256, 0, stream>>>(xb, wq_b, bq, q_b);
    k_attn<<<dim3(NN / 128, HH, BB), 256, 0, stream>>>(q_b, k_b, v_t, xt_o /* o reuses xtf */);
    k_oproj<<<dim3((BB * NN / 128) * 12), 256, 0, stream>>>(xt_o, wp_b, bp, out);
}

// Round 18
// 228.452 us; speedup vs baseline: 1.0739x; 1.0739x over previous
//
#include <hip/hip_runtime.h>
#include <hip/hip_bf16.h>
#include <cstdint>

// ---- problem constants ----
#define BB 32
#define NN 1024
#define CC 768
#define MM 64
#define HH 12
#define DD 64

typedef float f4v __attribute__((ext_vector_type(4)));
typedef __bf16 bf8 __attribute__((ext_vector_type(8)));
typedef __bf16 bf4 __attribute__((ext_vector_type(4)));

__device__ __forceinline__ f4v mfma16(bf8 a, bf8 b, f4v c) {
    return __builtin_amdgcn_mfma_f32_16x16x32_bf16(a, b, c, 0, 0, 0);
}
__device__ __forceinline__ __bf16 f2bf(float f) { return (__bf16)f; }

__device__ __forceinline__ void gl2lds16(const void* g, void* lds) {
    __builtin_amdgcn_global_load_lds((const __attribute__((address_space(1))) void*)g,
                                     (__attribute__((address_space(3))) void*)lds, 16, 0, 0);
}

// ================= fragment-linear layout (lane-order) =================
// frag[tile16][kc32][lane64][8]: element (row, k) at
//   tile = row>>4, kc = k>>5, LANE = ((k>>3)&3)*16 + (row&15), e = k&7
// A wave's fragment load = base + l*8 -> one coalesced 1KB line; lane l gets
// exactly its MFMA fragment element (row = l&15, k = (l>>4)*8+e).
// Used for: xb, Wc/Wq/Wp, q, o, kf, vf, c_bmn, xt.

// ---------- all weights fp32 -> bf16; Wc/Wq/Wp FRAG-LINEAR, Wk/Wv row-major ----------
__global__ __launch_bounds__(256) void k_cvtW(
        const float* __restrict__ Wc, const float* __restrict__ Wq,
        const float* __restrict__ Wk, const float* __restrict__ Wv,
        const float* __restrict__ Wp,
        __bf16* __restrict__ wc, __bf16* __restrict__ wq,
        __bf16* __restrict__ wk, __bf16* __restrict__ wv,
        __bf16* __restrict__ wp) {
    const float* in; __bf16* out; int n4; int frag;
    switch (blockIdx.y) {
        case 0: in = Wc; out = wc; n4 = MM * CC / 4; frag = 1; break;
        case 1: in = Wq; out = wq; n4 = CC * CC / 4; frag = 1; break;
        case 2: in = Wk; out = wk; n4 = CC * CC / 4; frag = 0; break;
        case 3: in = Wv; out = wv; n4 = CC * CC / 4; frag = 0; break;
        default: in = Wp; out = wp; n4 = CC * CC / 4; frag = 1; break;
    }
    int i = blockIdx.x * 256 + threadIdx.x;
    if (i < n4) {
        float4 v = *(const float4*)&in[i * 4];
        bf4 o; o[0] = f2bf(v.x); o[1] = f2bf(v.y); o[2] = f2bf(v.z); o[3] = f2bf(v.w);
        if (frag) {
            int lin = i * 4, m = lin / CC, c = lin % CC;
            size_t off = ((size_t)((m >> 4) * 24 + (c >> 5))) * 512
                       + ((((c >> 3) & 3) * 16) + (m & 15)) * 8 + (c & 7);
            *(bf4*)&out[off] = o;
        } else {
            *(bf4*)&out[i * 4] = o;
        }
    }
}

// ---------- K0 (R15-verified): x -> xb FRAG-LINEAR  AND  xt FRAG-LINEAR-TRANSPOSED ----------
__global__ __launch_bounds__(256) void k_cvtx(const float* __restrict__ x,
        __bf16* __restrict__ xb, __bf16* __restrict__ xt) {
    int c0 = blockIdx.x * 64, n0 = blockIdx.y * 64, b = blockIdx.z;
    __shared__ __align__(16) __bf16 tileT[64 * 66];
    __shared__ __align__(16) __bf16 tileR[64 * 72];
    int t = threadIdx.x;
#pragma unroll
    for (int i = 0; i < 4; i++) {
        int idx = t + 256 * i, r = idx >> 4, cq = idx & 15;
        float4 v = *(const float4*)&x[((size_t)(b * NN + n0 + r)) * CC + c0 + cq * 4];
        float vv[4] = {v.x, v.y, v.z, v.w};
        bf4 o;
#pragma unroll
        for (int j = 0; j < 4; j++) {
            __bf16 bv = f2bf(vv[j]);
            o[j] = bv;
            tileT[(cq * 4 + j) * 66 + r] = bv;
        }
        *(bf4*)&tileR[r * 72 + cq * 4] = o;
    }
    __syncthreads();
    int gnt = b * 64 + (n0 >> 4);
    int kc0 = c0 >> 5;
    int lane = t & 63;
#pragma unroll
    for (int i = 0; i < 2; i++) {
        int idx = t + 256 * i;
        int nt_loc = idx >> 7, kc_loc = (idx >> 6) & 1;
        int row = nt_loc * 16 + (lane & 15);
        int col = kc_loc * 32 + (lane >> 4) * 8;
        bf8 v = *(const bf8*)&tileR[row * 72 + col];
        *(bf8*)&xb[((size_t)((gnt + nt_loc) * 24 + kc0 + kc_loc)) * 512 + lane * 8] = v;
    }
#pragma unroll
    for (int i = 0; i < 2; i++) {
        int idx = t + 256 * i;
        int bid = idx >> 6, lane2 = idx & 63;
        int ct_loc = bid >> 1, nc_loc = bid & 1;
        bf8 v2 = *(const bf8*)&tileT[(ct_loc * 16 + (lane2 & 15)) * 66 + nc_loc * 32 + (lane2 >> 4) * 8];
        *(bf8*)&xt[((size_t)((b * 48 + (c0 >> 4) + ct_loc) * 32 + (n0 >> 5) + nc_loc)) * 512 + lane2 * 8] = v2;
    }
}

// ---------- K1 (R15-verified): c_bmn = sigmoid(x@Wc^T + bc)/N -> FRAG-LINEAR cf ----------
__global__ __launch_bounds__(256) void k_cluster(const __bf16* __restrict__ xb,
        const __bf16* __restrict__ Wc, const float* __restrict__ bc,
        __bf16* __restrict__ cbmn) {
    int n0 = blockIdx.x * 128, b = blockIdx.y;
    __shared__ __align__(16) __bf16 ctile[64 * 136];
    int t = threadIdx.x, w = t >> 6, l = t & 63, quad = (l >> 4), l16 = l & 15;
    int nt0 = b * 64 + (n0 >> 4);
    f4v acc[2][4];
#pragma unroll
    for (int i = 0; i < 2; i++) for (int j = 0; j < 4; j++) acc[i][j] = (f4v)0.0f;
    for (int kc = 0; kc < 24; kc++) {
        bf8 afr[2], bfr[4];
#pragma unroll
        for (int sr = 0; sr < 2; sr++)
            afr[sr] = *(const bf8*)&xb[((size_t)((nt0 + w * 2 + sr) * 24 + kc)) * 512 + l * 8];
#pragma unroll
        for (int sc = 0; sc < 4; sc++)
            bfr[sc] = *(const bf8*)&Wc[((size_t)(sc * 24 + kc)) * 512 + l * 8];
#pragma unroll
        for (int sr = 0; sr < 2; sr++)
#pragma unroll
            for (int sc = 0; sc < 4; sc++)
                acc[sr][sc] = mfma16(afr[sr], bfr[sc], acc[sr][sc]);
    }
#pragma unroll
    for (int sr = 0; sr < 2; sr++)
#pragma unroll
        for (int sc = 0; sc < 4; sc++) {
            int m = sc * 16 + l16;
            float bias = bc[m];
#pragma unroll
            for (int r = 0; r < 4; r++) {
                float val = acc[sr][sc][r] + bias;
                val = 1.0f / (1.0f + __expf(-val));
                int nloc = w * 32 + sr * 16 + quad * 4 + r;
                ctile[m * 136 + nloc] = f2bf(val * (1.0f / 1024.0f));
            }
        }
    __syncthreads();
#pragma unroll
    for (int i = 0; i < 4; i++) {
        int idx = t + 256 * i, bid = idx >> 6, lane = idx & 63;
        int mt = bid >> 2, ncl = bid & 3;
        bf8 v = *(const bf8*)&ctile[(mt * 16 + (lane & 15)) * 136 + ncl * 32 + (lane >> 4) * 8];
        *(bf8*)&cbmn[((size_t)((b * 4 + mt) * 32 + (n0 >> 5) + ncl)) * 512 + lane * 8] = v;
    }
}

// ---------- K2 (R15-verified): z = sum_n cf * xtf ----------
__global__ __launch_bounds__(256) void k_z(const __bf16* __restrict__ cbmn,
        const __bf16* __restrict__ xt, float* __restrict__ z) {
    int c0 = blockIdx.x * 64, b = blockIdx.y;
    int t = threadIdx.x, w = t >> 6, l = t & 63, quad = l >> 4, l16 = l & 15;
    f4v acc[4];
#pragma unroll
    for (int j = 0; j < 4; j++) acc[j] = (f4v)0.0f;
    for (int nc = 0; nc < 32; nc++) {
        bf8 afr = *(const bf8*)&cbmn[((size_t)((b * 4 + w) * 32 + nc)) * 512 + l * 8];
#pragma unroll
        for (int sc = 0; sc < 4; sc++) {
            bf8 bfr = *(const bf8*)&xt[((size_t)((b * 48 + (c0 >> 4) + sc) * 32 + nc)) * 512 + l * 8];
            acc[sc] = mfma16(afr, bfr, acc[sc]);
        }
    }
#pragma unroll
    for (int sc = 0; sc < 4; sc++) {
        int cc = c0 + sc * 16 + l16;
#pragma unroll
        for (int r = 0; r < 4; r++) {
            int m = w * 16 + quad * 4 + r;
            z[((size_t)(b * MM + m)) * CC + cc] = acc[sc][r];
        }
    }
}

// ---------- K2b: L2-normalize rows of z, write bf16 (unchanged) ----------
__global__ __launch_bounds__(256) void k_znorm(const float* __restrict__ z, __bf16* __restrict__ zb) {
    int w = threadIdx.x >> 6, l = threadIdx.x & 63;
    int row = blockIdx.x * 4 + w;
    const float* zr = &z[(size_t)row * CC];
    float v[12]; float ss = 0.f;
#pragma unroll
    for (int i = 0; i < 12; i++) { v[i] = zr[l + i * 64]; ss += v[i] * v[i]; }
#pragma unroll
    for (int off = 32; off; off >>= 1) ss += __shfl_xor(ss, off);
    float s = 1.0f / fmaxf(sqrtf(ss), 1e-12f);
    __bf16* zo = &zb[(size_t)row * CC];
#pragma unroll
    for (int i = 0; i < 12; i++) zo[l + i * 64] = f2bf(v[i] * s);
}

// ---------- K3 (R14-verified): k/v projections -> FRAG-LINEAR kf/vf ----------
__global__ __launch_bounds__(256) void k_kv(const __bf16* __restrict__ zb,
        const __bf16* __restrict__ Wk, const float* __restrict__ bk,
        const __bf16* __restrict__ Wv, const float* __restrict__ bv,
        __bf16* __restrict__ kout, __bf16* __restrict__ vtout) {
    int ct = blockIdx.x, b = blockIdx.y, which = blockIdx.z;
    const __bf16* W = which ? Wv : Wk;
    const float* bias = which ? bv : bk;
    __shared__ __align__(16) __bf16 tile[128 * 72];
    int t = threadIdx.x, w = t >> 6, l = t & 63, quad = l >> 4, l16 = l & 15;
    int h0 = ct * 2;
    f4v acc[4][2];
#pragma unroll
    for (int i = 0; i < 4; i++) for (int j = 0; j < 2; j++) acc[i][j] = (f4v)0.0f;
    for (int k0 = 0; k0 < CC; k0 += 32) {
        bf8 afr[4], bfr[2];
#pragma unroll
        for (int sr = 0; sr < 4; sr++)
            afr[sr] = *(const bf8*)&zb[((size_t)(b * MM + sr * 16 + l16)) * CC + k0 + quad * 8];
#pragma unroll
        for (int sc = 0; sc < 2; sc++)
            bfr[sc] = *(const bf8*)&W[((size_t)(ct * 128 + w * 32 + sc * 16 + l16)) * CC + k0 + quad * 8];
#pragma unroll
        for (int sr = 0; sr < 4; sr++)
#pragma unroll
            for (int sc = 0; sc < 2; sc++)
                acc[sr][sc] = mfma16(afr[sr], bfr[sc], acc[sr][sc]);
    }
#pragma unroll
    for (int sr = 0; sr < 4; sr++)
#pragma unroll
        for (int sc = 0; sc < 2; sc++) {
            int col = w * 32 + sc * 16 + l16;
            float bb = bias[ct * 128 + col];
#pragma unroll
            for (int r = 0; r < 4; r++) {
                int m = sr * 16 + quad * 4 + r;
                __bf16 val = f2bf(acc[sr][sc][r] + bb);
                if (which == 0) tile[m * 136 + col] = val;
                else            tile[col * 72 + m] = val;
            }
        }
    __syncthreads();
#pragma unroll
    for (int i = 0; i < 4; i++) {
        int idx = t + 256 * i;
        int bid = idx >> 6, lane = idx & 63;
        int h_loc = bid >> 3, t4 = (bid >> 1) & 3, kc2 = bid & 1;
        int h = h0 + h_loc;
        if (which == 0) {
            int m = t4 * 16 + (lane & 15), d = kc2 * 32 + (lane >> 4) * 8;
            bf8 v = *(const bf8*)&tile[m * 136 + h_loc * 64 + d];
            *(bf8*)&kout[((size_t)(((b * HH + h) * 4 + t4) * 2 + kc2)) * 512 + lane * 8] = v;
        } else {
            int d = t4 * 16 + (lane & 15), m = kc2 * 32 + (lane >> 4) * 8;
            bf8 v = *(const bf8*)&tile[(h_loc * 64 + d) * 72 + m];
            *(bf8*)&vtout[((size_t)(((b * HH + h) * 4 + t4) * 2 + kc2)) * 512 + lane * 8] = v;
        }
    }
}

// ======== HYBRID 128x128 GEMM, 4 waves in 2x2 grid, per-wave 64x64 ========
// R16-verified optimum of the occupancy sweep (2 blk@128x256=237.1, 3 blk@128x128
// =228.9, 4 blk@128x64=245.3): acc[4][4]=64 AGPR, ~160 regs < 170 @ 3 waves/SIMD.
// A staged depth-3 (24 KB), B reg-double-buffered, counted vmcnt; 3 co-resident
// unsynced blocks/CU cover each other's barrier drains.
#define STAGE_AF(Asrc, buf, kcs)                                                      \
    do {                                                                              \
        __bf16* _d = (buf);                                                           \
        gl2lds16(&(Asrc)[((size_t)((gt0 + w) * 24 + (kcs))) * 512 + l * 8], &_d[w * 512]); \
        gl2lds16(&(Asrc)[((size_t)((gt0 + w + 4) * 24 + (kcs))) * 512 + l * 8], &_d[(w + 4) * 512]); \
    } while (0)

#define GEMM_KLOOP_S(Asrc, Bsrc)                                                      \
    bf8 bcur[4], bnxt[4];                                                             \
    _Pragma("unroll")                                                                 \
    for (int sc = 0; sc < 4; sc++)                                                    \
        bcur[sc] = *(const bf8*)&(Bsrc)[((size_t)((jt * 8 + wn * 4 + sc) * 24)) * 512 + l * 8]; \
    STAGE_AF(Asrc, As3, 0);                                                           \
    STAGE_AF(Asrc, As3 + 4096, 1);                                                    \
    asm volatile("s_waitcnt vmcnt(2)" ::: "memory");                                  \
    __builtin_amdgcn_s_barrier();                                                     \
    for (int kt = 0; kt < 24; ++kt) {                                                 \
        const __bf16* As = As3 + (kt % 3) * 4096;                                     \
        if (kt < 23) {                                                                \
            _Pragma("unroll")                                                         \
            for (int sc = 0; sc < 4; sc++)                                            \
                bnxt[sc] = *(const bf8*)&(Bsrc)[((size_t)((jt * 8 + wn * 4 + sc) * 24 + kt + 1)) * 512 + l * 8]; \
        }                                                                             \
        bf8 afr[4];                                                                   \
        _Pragma("unroll")                                                             \
        for (int sr = 0; sr < 4; sr++)                                                \
            afr[sr] = *(const bf8*)&As[(wm * 4 + sr) * 512 + l * 8];                  \
        __builtin_amdgcn_sched_barrier(0);                                            \
        if (kt < 22) STAGE_AF(Asrc, As3 + ((kt + 2) % 3) * 4096, kt + 2);             \
        __builtin_amdgcn_s_setprio(1);                                                \
        _Pragma("unroll")                                                             \
        for (int sr = 0; sr < 4; sr++)                                                \
            _Pragma("unroll")                                                         \
            for (int sc = 0; sc < 4; sc++)                                            \
                acc[sr][sc] = mfma16(afr[sr], bcur[sc], acc[sr][sc]);                 \
        __builtin_amdgcn_s_setprio(0);                                                \
        if (kt < 23) {                                                                \
            _Pragma("unroll")                                                         \
            for (int sc = 0; sc < 4; sc++) bcur[sc] = bnxt[sc];                       \
        }                                                                             \
        if (kt < 22)       asm volatile("s_waitcnt vmcnt(6)" ::: "memory");           \
        else if (kt == 22) asm volatile("s_waitcnt vmcnt(4)" ::: "memory");           \
        __builtin_amdgcn_s_barrier();                                                 \
    }

// ---------- K4: q = xb @ Wq^T + bq -> q FRAG-LINEAR [nt][h][kcs][lane][8] ----------
__global__ __launch_bounds__(256, 3) void k_qproj(const __bf16* __restrict__ xb,
        const __bf16* __restrict__ Wq, const float* __restrict__ bq,
        __bf16* __restrict__ qb) {
    // 1536 blocks = 8 XCD x 192 (32 row-stripes x 6 jt per chunk)
    int orig = blockIdx.x;
    int lid = (orig & 7) * 192 + (orig >> 3);
    int jt = lid % 6;
    int gt0 = (lid / 6) * 8;   // 8 row-tiles = 128 rows

    __shared__ __align__(16) __bf16 As3[3 * 4096];  // 24 KB; epilogue (18 KB) aliases it
    int t = threadIdx.x, w = t >> 6, l = t & 63, quad = l >> 4, l16 = l & 15;
    int wm = w >> 1, wn = w & 1;   // 2x2 wave grid; per-wave 64 rows x 64 cols (1 head)
    f4v acc[4][4];
#pragma unroll
    for (int i = 0; i < 4; i++) for (int j = 0; j < 4; j++) acc[i][j] = (f4v)0.0f;

    GEMM_KLOOP_S(xb, Wq);

    // epilogue: 2 phases; phase p: the 2 waves with wn==p dump 128x64 (pad 72) of
    // head jt*2+p; all 256 threads then store frag-linear 1KB lines.
    __bf16* eb = As3;
    for (int p = 0; p < 2; ++p) {
        if (wn == p) {
#pragma unroll
            for (int sc = 0; sc < 4; sc++) {
                int col = jt * 128 + p * 64 + sc * 16 + l16;
                float bb = bq[col];
#pragma unroll
                for (int sr = 0; sr < 4; sr++)
#pragma unroll
                    for (int r = 0; r < 4; r++)
                        eb[(wm * 64 + sr * 16 + quad * 4 + r) * 72 + sc * 16 + l16] = f2bf(acc[sr][sc][r] + bb);
            }
        }
        __syncthreads();
        int h = jt * 2 + p;
#pragma unroll
        for (int i = 0; i < 4; i++) {
            int idx = t + 256 * i, nt = idx >> 7, kcs = (idx >> 6) & 1, lane = idx & 63;
            bf8 v = *(const bf8*)&eb[(nt * 16 + (lane & 15)) * 72 + kcs * 32 + (lane >> 4) * 8];
            *(bf8*)&qb[((size_t)(((gt0 + nt) * 12 + h) * 2 + kcs)) * 512 + lane * 8] = v;
        }
        __syncthreads();
    }
}

// ---------- K5 (R15-verified): attention (q, kf, vf all frag-linear) ----------
#define QS 72
__global__ __launch_bounds__(256) void k_attn(const __bf16* __restrict__ qb,
        const __bf16* __restrict__ kb, const __bf16* __restrict__ vt,
        __bf16* __restrict__ ob) {
    int n0 = blockIdx.x * 128, h = blockIdx.y, b = blockIdx.z;
    __shared__ __align__(16) __bf16 ps[128 * QS];
    int t = threadIdx.x, w = t >> 6, l = t & 63, quad = l >> 4, l16 = l & 15;
    size_t bh = (size_t)(b * HH + h);
    int nt0 = b * 64 + (n0 >> 4);

    f4v sacc[2][4];
#pragma unroll
    for (int i = 0; i < 2; i++) for (int j = 0; j < 4; j++) sacc[i][j] = (f4v)0.0f;
#pragma unroll
    for (int kc = 0; kc < 2; kc++) {
        bf8 afr[2], bfr[4];
#pragma unroll
        for (int sr = 0; sr < 2; sr++)
            afr[sr] = *(const bf8*)&qb[((size_t)(((nt0 + w * 2 + sr) * 12 + h) * 2 + kc)) * 512 + l * 8];
#pragma unroll
        for (int sc = 0; sc < 4; sc++)
            bfr[sc] = *(const bf8*)&kb[((size_t)((bh * 4 + sc) * 2 + kc)) * 512 + l * 8];
#pragma unroll
        for (int sr = 0; sr < 2; sr++)
#pragma unroll
            for (int sc = 0; sc < 4; sc++)
                sacc[sr][sc] = mfma16(afr[sr], bfr[sc], sacc[sr][sc]);
    }
#pragma unroll
    for (int sr = 0; sr < 2; sr++) {
#pragma unroll
        for (int r = 0; r < 4; r++) {
            float mx = -1e30f;
#pragma unroll
            for (int sc = 0; sc < 4; sc++) mx = fmaxf(mx, sacc[sr][sc][r] * 0.125f);
#pragma unroll
            for (int off = 1; off < 16; off <<= 1) mx = fmaxf(mx, __shfl_xor(mx, off));
            float e[4]; float sum = 0.f;
#pragma unroll
            for (int sc = 0; sc < 4; sc++) { e[sc] = __expf(sacc[sr][sc][r] * 0.125f - mx); sum += e[sc]; }
#pragma unroll
            for (int off = 1; off < 16; off <<= 1) sum += __shfl_xor(sum, off);
            float inv = 1.0f / sum;
            int row = w * 32 + sr * 16 + quad * 4 + r;
#pragma unroll
            for (int sc = 0; sc < 4; sc++) ps[row * QS + sc * 16 + l16] = f2bf(e[sc] * inv);
        }
    }
    f4v oacc[2][4];
#pragma unroll
    for (int i = 0; i < 2; i++) for (int j = 0; j < 4; j++) oacc[i][j] = (f4v)0.0f;
#pragma unroll
    for (int kc = 0; kc < 2; kc++) {
        bf8 afr[2], bfr[4];
#pragma unroll
        for (int sr = 0; sr < 2; sr++)
            afr[sr] = *(const bf8*)&ps[(w * 32 + sr * 16 + l16) * QS + kc * 32 + quad * 8];
#pragma unroll
        for (int sc = 0; sc < 4; sc++)
            bfr[sc] = *(const bf8*)&vt[((size_t)((bh * 4 + sc) * 2 + kc)) * 512 + l * 8];
#pragma unroll
        for (int sr = 0; sr < 2; sr++)
#pragma unroll
            for (int sc = 0; sc < 4; sc++)
                oacc[sr][sc] = mfma16(afr[sr], bfr[sc], oacc[sr][sc]);
    }
#pragma unroll
    for (int sr = 0; sr < 2; sr++)
#pragma unroll
        for (int sc = 0; sc < 4; sc++) {
            int row = w * 32 + sr * 16;
#pragma unroll
            for (int r = 0; r < 4; r++)
                ps[(row + quad * 4 + r) * QS + sc * 16 + l16] = f2bf(oacc[sr][sc][r]);
        }
    __syncthreads();
#pragma unroll
    for (int i = 0; i < 4; i++) {
        int idx = t + 256 * i, nt = idx >> 7, kcs = (idx >> 6) & 1, lane = idx & 63;
        bf8 v = *(const bf8*)&ps[(nt * 16 + (lane & 15)) * QS + kcs * 32 + (lane >> 4) * 8];
        *(bf8*)&ob[((size_t)((nt0 + nt) * 24 + h * 2 + kcs)) * 512 + lane * 8] = v;
    }
}

// ---------- K6: out = o @ Wp^T + bp  (o frag-linear in, fp32 row-major out) ----------
__global__ __launch_bounds__(256, 3) void k_oproj(const __bf16* __restrict__ ob,
        const __bf16* __restrict__ Wp, const float* __restrict__ bp,
        float* __restrict__ out) {
    int orig = blockIdx.x;
    int lid = (orig & 7) * 192 + (orig >> 3);
    int jt = lid % 6;
    int gt0 = (lid / 6) * 8;
    size_t arow0 = (size_t)(lid / 6) * 128;

    __shared__ __align__(16) __bf16 As3[3 * 4096];  // 24 KB; fp32 epilogue (16 KB/qphase) aliases it
    int t = threadIdx.x, w = t >> 6, l = t & 63, quad = l >> 4, l16 = l & 15;
    int wm = w >> 1, wn = w & 1;
    f4v acc[4][4];
#pragma unroll
    for (int i = 0; i < 4; i++) for (int j = 0; j < 4; j++) acc[i][j] = (f4v)0.0f;

    GEMM_KLOOP_S(ob, Wp);

    // epilogue: 4 quarter-phases (p=wn, hm=wm): single wave dumps 64x64 fp32
    // (pad 68, 16 KB <= 24 KB), all 256 threads store full float4 lines.
    float* ebf = (float*)As3;
    for (int p = 0; p < 2; ++p) {
        for (int hm = 0; hm < 2; ++hm) {
            if (wn == p && wm == hm) {
#pragma unroll
                for (int sc = 0; sc < 4; sc++) {
                    int col = jt * 128 + p * 64 + sc * 16 + l16;
                    float bb = bp[col];
#pragma unroll
                    for (int sr = 0; sr < 4; sr++)
#pragma unroll
                        for (int r = 0; r < 4; r++)
                            ebf[(sr * 16 + quad * 4 + r) * 68 + sc * 16 + l16] = acc[sr][sc][r] + bb;
                }
            }
            __syncthreads();
#pragma unroll
            for (int i = 0; i < 4; i++) {
                int idx = t + 256 * i, row = idx >> 4, c4 = idx & 15;
                *(float4*)&out[(arow0 + hm * 64 + row) * CC + jt * 128 + p * 64 + c4 * 4] =
                    *(const float4*)&ebf[row * 68 + c4 * 4];
            }
            __syncthreads();
        }
    }
}

extern "C" void kernel_launch(void* const* d_in, const int* in_sizes, int n_in,
                              void* d_out, int out_size, void* d_ws, size_t ws_size,
                              hipStream_t stream) {
    (void)in_sizes; (void)n_in; (void)out_size; (void)ws_size;
    const float* x  = (const float*)d_in[0];
    const float* Wc = (const float*)d_in[1];
    const float* bc = (const float*)d_in[2];
    const float* Wq = (const float*)d_in[3];
    const float* bq = (const float*)d_in[4];
    const float* Wk = (const float*)d_in[5];
    const float* bk = (const float*)d_in[6];
    const float* Wv = (const float*)d_in[7];
    const float* bv = (const float*)d_in[8];
    const float* Wp = (const float*)d_in[9];
    const float* bp = (const float*)d_in[10];
    float* out = (float*)d_out;

    char* ws = (char*)d_ws;
    size_t off = 0;
    auto alloc = [&](size_t bytes) { void* p = ws + off; off = (off + bytes + 255) & ~(size_t)255; return p; };
    __bf16* wc_b = (__bf16*)alloc((size_t)MM * CC * 2);
    __bf16* wq_b = (__bf16*)alloc((size_t)CC * CC * 2);
    __bf16* wk_b = (__bf16*)alloc((size_t)CC * CC * 2);
    __bf16* wv_b = (__bf16*)alloc((size_t)CC * CC * 2);
    __bf16* wp_b = (__bf16*)alloc((size_t)CC * CC * 2);
    __bf16* xb   = (__bf16*)alloc((size_t)BB * NN * CC * 2);
    __bf16* xt_o = (__bf16*)alloc((size_t)BB * NN * CC * 2);  // xtf, reused as o (frag)
    __bf16* q_b  = (__bf16*)alloc((size_t)BB * NN * CC * 2);
    __bf16* c_bmn= (__bf16*)alloc((size_t)BB * MM * NN * 2);
    float*  z_f  = (float*) alloc((size_t)BB * MM * CC * 4);
    __bf16* z_b  = (__bf16*)alloc((size_t)BB * MM * CC * 2);
    __bf16* k_b  = (__bf16*)alloc((size_t)BB * HH * MM * DD * 2);
    __bf16* v_t  = (__bf16*)alloc((size_t)BB * HH * MM * DD * 2);

    k_cvtW<<<dim3((CC * CC / 4 + 255) / 256, 5), 256, 0, stream>>>(
        Wc, Wq, Wk, Wv, Wp, wc_b, wq_b, wk_b, wv_b, wp_b);

    k_cvtx<<<dim3(CC / 64, NN / 64, BB), 256, 0, stream>>>(x, xb, xt_o);
    k_cluster<<<dim3(NN / 128, BB), 256, 0, stream>>>(xb, wc_b, bc, c_bmn);
    k_z<<<dim3(CC / 64, BB), 256, 0, stream>>>(c_bmn, xt_o, z_f);
    k_znorm<<<(BB * MM) / 4, 256, 0, stream>>>(z_f, z_b);
    k_kv<<<dim3(CC / 128, BB, 2), 256, 0, stream>>>(z_b, wk_b, bk, wv_b, bv, k_b, v_t);
    k_qproj<<<dim3((BB * NN / 128) * 6), 256, 0, stream>>>(xb, wq_b, bq, q_b);
    k_attn<<<dim3(NN / 128, HH, BB), 256, 0, stream>>>(q_b, k_b, v_t, xt_o /* o reuses xtf */);
    k_oproj<<<dim3((BB * NN / 128) * 6), 256, 0, stream>>>(xt_o, wp_b, bp, out);
}

// Round 21
// 228.294 us; speedup vs baseline: 1.0746x; 1.0007x over previous
//
#include <hip/hip_runtime.h>
#include <hip/hip_bf16.h>
#include <cstdint>

// ---- problem constants ----
#define BB 32
#define NN 1024
#define CC 768
#define MM 64
#define HH 12
#define DD 64

typedef float f4v __attribute__((ext_vector_type(4)));
typedef __bf16 bf8 __attribute__((ext_vector_type(8)));
typedef __bf16 bf4 __attribute__((ext_vector_type(4)));

__device__ __forceinline__ f4v mfma16(bf8 a, bf8 b, f4v c) {
    return __builtin_amdgcn_mfma_f32_16x16x32_bf16(a, b, c, 0, 0, 0);
}
__device__ __forceinline__ __bf16 f2bf(float f) { return (__bf16)f; }

__device__ __forceinline__ void gl2lds16(const void* g, void* lds) {
    __builtin_amdgcn_global_load_lds((const __attribute__((address_space(1))) void*)g,
                                     (__attribute__((address_space(3))) void*)lds, 16, 0, 0);
}

// ================= fragment-linear layout (lane-order) =================
// frag[tile16][kc32][lane64][8]: element (row, k) at
//   tile = row>>4, kc = k>>5, LANE = ((k>>3)&3)*16 + (row&15), e = k&7
// A wave's fragment load = base + l*8 -> one coalesced 1KB line; lane l gets
// exactly its MFMA fragment element (row = l&15, k = (l>>4)*8+e).
// Used for: xb, Wc/Wq/Wp, q, o, kf, vf, c_bmn, xt.

// ---------- all weights fp32 -> bf16; Wc/Wq/Wp FRAG-LINEAR, Wk/Wv row-major ----------
__global__ __launch_bounds__(256) void k_cvtW(
        const float* __restrict__ Wc, const float* __restrict__ Wq,
        const float* __restrict__ Wk, const float* __restrict__ Wv,
        const float* __restrict__ Wp,
        __bf16* __restrict__ wc, __bf16* __restrict__ wq,
        __bf16* __restrict__ wk, __bf16* __restrict__ wv,
        __bf16* __restrict__ wp) {
    const float* in; __bf16* out; int n4; int frag;
    switch (blockIdx.y) {
        case 0: in = Wc; out = wc; n4 = MM * CC / 4; frag = 1; break;
        case 1: in = Wq; out = wq; n4 = CC * CC / 4; frag = 1; break;
        case 2: in = Wk; out = wk; n4 = CC * CC / 4; frag = 0; break;
        case 3: in = Wv; out = wv; n4 = CC * CC / 4; frag = 0; break;
        default: in = Wp; out = wp; n4 = CC * CC / 4; frag = 1; break;
    }
    int i = blockIdx.x * 256 + threadIdx.x;
    if (i < n4) {
        float4 v = *(const float4*)&in[i * 4];
        bf4 o; o[0] = f2bf(v.x); o[1] = f2bf(v.y); o[2] = f2bf(v.z); o[3] = f2bf(v.w);
        if (frag) {
            int lin = i * 4, m = lin / CC, c = lin % CC;
            size_t off = ((size_t)((m >> 4) * 24 + (c >> 5))) * 512
                       + ((((c >> 3) & 3) * 16) + (m & 15)) * 8 + (c & 7);
            *(bf4*)&out[off] = o;
        } else {
            *(bf4*)&out[i * 4] = o;
        }
    }
}

// ---------- K0 (R15-verified): x -> xb FRAG-LINEAR  AND  xt FRAG-LINEAR-TRANSPOSED ----------
__global__ __launch_bounds__(256) void k_cvtx(const float* __restrict__ x,
        __bf16* __restrict__ xb, __bf16* __restrict__ xt) {
    int c0 = blockIdx.x * 64, n0 = blockIdx.y * 64, b = blockIdx.z;
    __shared__ __align__(16) __bf16 tileT[64 * 66];
    __shared__ __align__(16) __bf16 tileR[64 * 72];
    int t = threadIdx.x;
#pragma unroll
    for (int i = 0; i < 4; i++) {
        int idx = t + 256 * i, r = idx >> 4, cq = idx & 15;
        float4 v = *(const float4*)&x[((size_t)(b * NN + n0 + r)) * CC + c0 + cq * 4];
        float vv[4] = {v.x, v.y, v.z, v.w};
        bf4 o;
#pragma unroll
        for (int j = 0; j < 4; j++) {
            __bf16 bv = f2bf(vv[j]);
            o[j] = bv;
            tileT[(cq * 4 + j) * 66 + r] = bv;
        }
        *(bf4*)&tileR[r * 72 + cq * 4] = o;
    }
    __syncthreads();
    int gnt = b * 64 + (n0 >> 4);
    int kc0 = c0 >> 5;
    int lane = t & 63;
#pragma unroll
    for (int i = 0; i < 2; i++) {
        int idx = t + 256 * i;
        int nt_loc = idx >> 7, kc_loc = (idx >> 6) & 1;
        int row = nt_loc * 16 + (lane & 15);
        int col = kc_loc * 32 + (lane >> 4) * 8;
        bf8 v = *(const bf8*)&tileR[row * 72 + col];
        *(bf8*)&xb[((size_t)((gnt + nt_loc) * 24 + kc0 + kc_loc)) * 512 + lane * 8] = v;
    }
#pragma unroll
    for (int i = 0; i < 2; i++) {
        int idx = t + 256 * i;
        int bid = idx >> 6, lane2 = idx & 63;
        int ct_loc = bid >> 1, nc_loc = bid & 1;
        bf8 v2 = *(const bf8*)&tileT[(ct_loc * 16 + (lane2 & 15)) * 66 + nc_loc * 32 + (lane2 >> 4) * 8];
        *(bf8*)&xt[((size_t)((b * 48 + (c0 >> 4) + ct_loc) * 32 + (n0 >> 5) + nc_loc)) * 512 + lane2 * 8] = v2;
    }
}

// ---------- K1 (R15-verified): c_bmn = sigmoid(x@Wc^T + bc)/N -> FRAG-LINEAR cf ----------
__global__ __launch_bounds__(256) void k_cluster(const __bf16* __restrict__ xb,
        const __bf16* __restrict__ Wc, const float* __restrict__ bc,
        __bf16* __restrict__ cbmn) {
    int n0 = blockIdx.x * 128, b = blockIdx.y;
    __shared__ __align__(16) __bf16 ctile[64 * 136];
    int t = threadIdx.x, w = t >> 6, l = t & 63, quad = (l >> 4), l16 = l & 15;
    int nt0 = b * 64 + (n0 >> 4);
    f4v acc[2][4];
#pragma unroll
    for (int i = 0; i < 2; i++) for (int j = 0; j < 4; j++) acc[i][j] = (f4v)0.0f;
    for (int kc = 0; kc < 24; kc++) {
        bf8 afr[2], bfr[4];
#pragma unroll
        for (int sr = 0; sr < 2; sr++)
            afr[sr] = *(const bf8*)&xb[((size_t)((nt0 + w * 2 + sr) * 24 + kc)) * 512 + l * 8];
#pragma unroll
        for (int sc = 0; sc < 4; sc++)
            bfr[sc] = *(const bf8*)&Wc[((size_t)(sc * 24 + kc)) * 512 + l * 8];
#pragma unroll
        for (int sr = 0; sr < 2; sr++)
#pragma unroll
            for (int sc = 0; sc < 4; sc++)
                acc[sr][sc] = mfma16(afr[sr], bfr[sc], acc[sr][sc]);
    }
#pragma unroll
    for (int sr = 0; sr < 2; sr++)
#pragma unroll
        for (int sc = 0; sc < 4; sc++) {
            int m = sc * 16 + l16;
            float bias = bc[m];
#pragma unroll
            for (int r = 0; r < 4; r++) {
                float val = acc[sr][sc][r] + bias;
                val = 1.0f / (1.0f + __expf(-val));
                int nloc = w * 32 + sr * 16 + quad * 4 + r;
                ctile[m * 136 + nloc] = f2bf(val * (1.0f / 1024.0f));
            }
        }
    __syncthreads();
#pragma unroll
    for (int i = 0; i < 4; i++) {
        int idx = t + 256 * i, bid = idx >> 6, lane = idx & 63;
        int mt = bid >> 2, ncl = bid & 3;
        bf8 v = *(const bf8*)&ctile[(mt * 16 + (lane & 15)) * 136 + ncl * 32 + (lane >> 4) * 8];
        *(bf8*)&cbmn[((size_t)((b * 4 + mt) * 32 + (n0 >> 5) + ncl)) * 512 + lane * 8] = v;
    }
}

// ---------- K2 (R15-verified): z = sum_n cf * xtf ----------
__global__ __launch_bounds__(256) void k_z(const __bf16* __restrict__ cbmn,
        const __bf16* __restrict__ xt, float* __restrict__ z) {
    int c0 = blockIdx.x * 64, b = blockIdx.y;
    int t = threadIdx.x, w = t >> 6, l = t & 63, quad = l >> 4, l16 = l & 15;
    f4v acc[4];
#pragma unroll
    for (int j = 0; j < 4; j++) acc[j] = (f4v)0.0f;
    for (int nc = 0; nc < 32; nc++) {
        bf8 afr = *(const bf8*)&cbmn[((size_t)((b * 4 + w) * 32 + nc)) * 512 + l * 8];
#pragma unroll
        for (int sc = 0; sc < 4; sc++) {
            bf8 bfr = *(const bf8*)&xt[((size_t)((b * 48 + (c0 >> 4) + sc) * 32 + nc)) * 512 + l * 8];
            acc[sc] = mfma16(afr, bfr, acc[sc]);
        }
    }
#pragma unroll
    for (int sc = 0; sc < 4; sc++) {
        int cc = c0 + sc * 16 + l16;
#pragma unroll
        for (int r = 0; r < 4; r++) {
            int m = w * 16 + quad * 4 + r;
            z[((size_t)(b * MM + m)) * CC + cc] = acc[sc][r];
        }
    }
}

// ---------- K2b: L2-normalize rows of z, write bf16 (unchanged) ----------
__global__ __launch_bounds__(256) void k_znorm(const float* __restrict__ z, __bf16* __restrict__ zb) {
    int w = threadIdx.x >> 6, l = threadIdx.x & 63;
    int row = blockIdx.x * 4 + w;
    const float* zr = &z[(size_t)row * CC];
    float v[12]; float ss = 0.f;
#pragma unroll
    for (int i = 0; i < 12; i++) { v[i] = zr[l + i * 64]; ss += v[i] * v[i]; }
#pragma unroll
    for (int off = 32; off; off >>= 1) ss += __shfl_xor(ss, off);
    float s = 1.0f / fmaxf(sqrtf(ss), 1e-12f);
    __bf16* zo = &zb[(size_t)row * CC];
#pragma unroll
    for (int i = 0; i < 12; i++) zo[l + i * 64] = f2bf(v[i] * s);
}

// ---------- K3 (R14-verified): k/v projections -> FRAG-LINEAR kf/vf ----------
__global__ __launch_bounds__(256) void k_kv(const __bf16* __restrict__ zb,
        const __bf16* __restrict__ Wk, const float* __restrict__ bk,
        const __bf16* __restrict__ Wv, const float* __restrict__ bv,
        __bf16* __restrict__ kout, __bf16* __restrict__ vtout) {
    int ct = blockIdx.x, b = blockIdx.y, which = blockIdx.z;
    const __bf16* W = which ? Wv : Wk;
    const float* bias = which ? bv : bk;
    __shared__ __align__(16) __bf16 tile[128 * 72];
    int t = threadIdx.x, w = t >> 6, l = t & 63, quad = l >> 4, l16 = l & 15;
    int h0 = ct * 2;
    f4v acc[4][2];
#pragma unroll
    for (int i = 0; i < 4; i++) for (int j = 0; j < 2; j++) acc[i][j] = (f4v)0.0f;
    for (int k0 = 0; k0 < CC; k0 += 32) {
        bf8 afr[4], bfr[2];
#pragma unroll
        for (int sr = 0; sr < 4; sr++)
            afr[sr] = *(const bf8*)&zb[((size_t)(b * MM + sr * 16 + l16)) * CC + k0 + quad * 8];
#pragma unroll
        for (int sc = 0; sc < 2; sc++)
            bfr[sc] = *(const bf8*)&W[((size_t)(ct * 128 + w * 32 + sc * 16 + l16)) * CC + k0 + quad * 8];
#pragma unroll
        for (int sr = 0; sr < 4; sr++)
#pragma unroll
            for (int sc = 0; sc < 2; sc++)
                acc[sr][sc] = mfma16(afr[sr], bfr[sc], acc[sr][sc]);
    }
#pragma unroll
    for (int sr = 0; sr < 4; sr++)
#pragma unroll
        for (int sc = 0; sc < 2; sc++) {
            int col = w * 32 + sc * 16 + l16;
            float bb = bias[ct * 128 + col];
#pragma unroll
            for (int r = 0; r < 4; r++) {
                int m = sr * 16 + quad * 4 + r;
                __bf16 val = f2bf(acc[sr][sc][r] + bb);
                if (which == 0) tile[m * 136 + col] = val;
                else            tile[col * 72 + m] = val;
            }
        }
    __syncthreads();
#pragma unroll
    for (int i = 0; i < 4; i++) {
        int idx = t + 256 * i;
        int bid = idx >> 6, lane = idx & 63;
        int h_loc = bid >> 3, t4 = (bid >> 1) & 3, kc2 = bid & 1;
        int h = h0 + h_loc;
        if (which == 0) {
            int m = t4 * 16 + (lane & 15), d = kc2 * 32 + (lane >> 4) * 8;
            bf8 v = *(const bf8*)&tile[m * 136 + h_loc * 64 + d];
            *(bf8*)&kout[((size_t)(((b * HH + h) * 4 + t4) * 2 + kc2)) * 512 + lane * 8] = v;
        } else {
            int d = t4 * 16 + (lane & 15), m = kc2 * 32 + (lane >> 4) * 8;
            bf8 v = *(const bf8*)&tile[(h_loc * 64 + d) * 72 + m];
            *(bf8*)&vtout[((size_t)(((b * HH + h) * 4 + t4) * 2 + kc2)) * 512 + lane * 8] = v;
        }
    }
}

// ======== HYBRID 128x128 GEMM, 4 waves in 2x2 grid, per-wave 64x64 ========
// R16-verified optimum of the occupancy sweep (2 blk@128x256=237.1, 3 blk@128x128
// =228.9, 4 blk@128x64=245.3): acc[4][4]=64 AGPR, ~160 regs < 170 @ 3 waves/SIMD.
// A staged depth-3 (24 KB), B reg-double-buffered, counted vmcnt; 3 co-resident
// unsynced blocks/CU cover each other's barrier drains.
#define STAGE_AF(Asrc, buf, kcs)                                                      \
    do {                                                                              \
        __bf16* _d = (buf);                                                           \
        gl2lds16(&(Asrc)[((size_t)((gt0 + w) * 24 + (kcs))) * 512 + l * 8], &_d[w * 512]); \
        gl2lds16(&(Asrc)[((size_t)((gt0 + w + 4) * 24 + (kcs))) * 512 + l * 8], &_d[(w + 4) * 512]); \
    } while (0)

#define GEMM_KLOOP_S(Asrc, Bsrc)                                                      \
    bf8 bcur[4], bnxt[4];                                                             \
    _Pragma("unroll")                                                                 \
    for (int sc = 0; sc < 4; sc++)                                                    \
        bcur[sc] = *(const bf8*)&(Bsrc)[((size_t)((jt * 8 + wn * 4 + sc) * 24)) * 512 + l * 8]; \
    STAGE_AF(Asrc, As3, 0);                                                           \
    STAGE_AF(Asrc, As3 + 4096, 1);                                                    \
    asm volatile("s_waitcnt vmcnt(2)" ::: "memory");                                  \
    __builtin_amdgcn_s_barrier();                                                     \
    for (int kt = 0; kt < 24; ++kt) {                                                 \
        const __bf16* As = As3 + (kt % 3) * 4096;                                     \
        if (kt < 23) {                                                                \
            _Pragma("unroll")                                                         \
            for (int sc = 0; sc < 4; sc++)                                            \
                bnxt[sc] = *(const bf8*)&(Bsrc)[((size_t)((jt * 8 + wn * 4 + sc) * 24 + kt + 1)) * 512 + l * 8]; \
        }                                                                             \
        bf8 afr[4];                                                                   \
        _Pragma("unroll")                                                             \
        for (int sr = 0; sr < 4; sr++)                                                \
            afr[sr] = *(const bf8*)&As[(wm * 4 + sr) * 512 + l * 8];                  \
        __builtin_amdgcn_sched_barrier(0);                                            \
        if (kt < 22) STAGE_AF(Asrc, As3 + ((kt + 2) % 3) * 4096, kt + 2);             \
        __builtin_amdgcn_s_setprio(1);                                                \
        _Pragma("unroll")                                                             \
        for (int sr = 0; sr < 4; sr++)                                                \
            _Pragma("unroll")                                                         \
            for (int sc = 0; sc < 4; sc++)                                            \
                acc[sr][sc] = mfma16(afr[sr], bcur[sc], acc[sr][sc]);                 \
        __builtin_amdgcn_s_setprio(0);                                                \
        if (kt < 23) {                                                                \
            _Pragma("unroll")                                                         \
            for (int sc = 0; sc < 4; sc++) bcur[sc] = bnxt[sc];                       \
        }                                                                             \
        if (kt < 22)       asm volatile("s_waitcnt vmcnt(6)" ::: "memory");           \
        else if (kt == 22) asm volatile("s_waitcnt vmcnt(4)" ::: "memory");           \
        __builtin_amdgcn_s_barrier();                                                 \
    }

// ---------- K4: q = xb @ Wq^T + bq -> q FRAG-LINEAR [nt][h][kcs][lane][8] ----------
__global__ __launch_bounds__(256, 3) void k_qproj(const __bf16* __restrict__ xb,
        const __bf16* __restrict__ Wq, const float* __restrict__ bq,
        __bf16* __restrict__ qb) {
    // 1536 blocks = 8 XCD x 192 (32 row-stripes x 6 jt per chunk)
    int orig = blockIdx.x;
    int lid = (orig & 7) * 192 + (orig >> 3);
    int jt = lid % 6;
    int gt0 = (lid / 6) * 8;   // 8 row-tiles = 128 rows

    __shared__ __align__(16) __bf16 As3[3 * 4096];  // 24 KB; epilogue (18 KB) aliases it
    int t = threadIdx.x, w = t >> 6, l = t & 63, quad = l >> 4, l16 = l & 15;
    int wm = w >> 1, wn = w & 1;   // 2x2 wave grid; per-wave 64 rows x 64 cols (1 head)
    f4v acc[4][4];
#pragma unroll
    for (int i = 0; i < 4; i++) for (int j = 0; j < 4; j++) acc[i][j] = (f4v)0.0f;

    GEMM_KLOOP_S(xb, Wq);

    // epilogue: 2 phases; phase p: the 2 waves with wn==p dump 128x64 (pad 72) of
    // head jt*2+p; all 256 threads then store frag-linear 1KB lines.
    __bf16* eb = As3;
    for (int p = 0; p < 2; ++p) {
        if (wn == p) {
#pragma unroll
            for (int sc = 0; sc < 4; sc++) {
                int col = jt * 128 + p * 64 + sc * 16 + l16;
                float bb = bq[col];
#pragma unroll
                for (int sr = 0; sr < 4; sr++)
#pragma unroll
                    for (int r = 0; r < 4; r++)
                        eb[(wm * 64 + sr * 16 + quad * 4 + r) * 72 + sc * 16 + l16] = f2bf(acc[sr][sc][r] + bb);
            }
        }
        __syncthreads();
        int h = jt * 2 + p;
#pragma unroll
        for (int i = 0; i < 4; i++) {
            int idx = t + 256 * i, nt = idx >> 7, kcs = (idx >> 6) & 1, lane = idx & 63;
            bf8 v = *(const bf8*)&eb[(nt * 16 + (lane & 15)) * 72 + kcs * 32 + (lane >> 4) * 8];
            *(bf8*)&qb[((size_t)(((gt0 + nt) * 12 + h) * 2 + kcs)) * 512 + lane * 8] = v;
        }
        __syncthreads();
    }
}

// ---------- K5 (R15-verified): attention (q, kf, vf all frag-linear) ----------
#define QS 72
__global__ __launch_bounds__(256) void k_attn(const __bf16* __restrict__ qb,
        const __bf16* __restrict__ kb, const __bf16* __restrict__ vt,
        __bf16* __restrict__ ob) {
    int n0 = blockIdx.x * 128, h = blockIdx.y, b = blockIdx.z;
    __shared__ __align__(16) __bf16 ps[128 * QS];
    int t = threadIdx.x, w = t >> 6, l = t & 63, quad = l >> 4, l16 = l & 15;
    size_t bh = (size_t)(b * HH + h);
    int nt0 = b * 64 + (n0 >> 4);

    f4v sacc[2][4];
#pragma unroll
    for (int i = 0; i < 2; i++) for (int j = 0; j < 4; j++) sacc[i][j] = (f4v)0.0f;
#pragma unroll
    for (int kc = 0; kc < 2; kc++) {
        bf8 afr[2], bfr[4];
#pragma unroll
        for (int sr = 0; sr < 2; sr++)
            afr[sr] = *(const bf8*)&qb[((size_t)(((nt0 + w * 2 + sr) * 12 + h) * 2 + kc)) * 512 + l * 8];
#pragma unroll
        for (int sc = 0; sc < 4; sc++)
            bfr[sc] = *(const bf8*)&kb[((size_t)((bh * 4 + sc) * 2 + kc)) * 512 + l * 8];
#pragma unroll
        for (int sr = 0; sr < 2; sr++)
#pragma unroll
            for (int sc = 0; sc < 4; sc++)
                sacc[sr][sc] = mfma16(afr[sr], bfr[sc], sacc[sr][sc]);
    }
#pragma unroll
    for (int sr = 0; sr < 2; sr++) {
#pragma unroll
        for (int r = 0; r < 4; r++) {
            float mx = -1e30f;
#pragma unroll
            for (int sc = 0; sc < 4; sc++) mx = fmaxf(mx, sacc[sr][sc][r] * 0.125f);
#pragma unroll
            for (int off = 1; off < 16; off <<= 1) mx = fmaxf(mx, __shfl_xor(mx, off));
            float e[4]; float sum = 0.f;
#pragma unroll
            for (int sc = 0; sc < 4; sc++) { e[sc] = __expf(sacc[sr][sc][r] * 0.125f - mx); sum += e[sc]; }
#pragma unroll
            for (int off = 1; off < 16; off <<= 1) sum += __shfl_xor(sum, off);
            float inv = 1.0f / sum;
            int row = w * 32 + sr * 16 + quad * 4 + r;
#pragma unroll
            for (int sc = 0; sc < 4; sc++) ps[row * QS + sc * 16 + l16] = f2bf(e[sc] * inv);
        }
    }
    f4v oacc[2][4];
#pragma unroll
    for (int i = 0; i < 2; i++) for (int j = 0; j < 4; j++) oacc[i][j] = (f4v)0.0f;
#pragma unroll
    for (int kc = 0; kc < 2; kc++) {
        bf8 afr[2], bfr[4];
#pragma unroll
        for (int sr = 0; sr < 2; sr++)
            afr[sr] = *(const bf8*)&ps[(w * 32 + sr * 16 + l16) * QS + kc * 32 + quad * 8];
#pragma unroll
        for (int sc = 0; sc < 4; sc++)
            bfr[sc] = *(const bf8*)&vt[((size_t)((bh * 4 + sc) * 2 + kc)) * 512 + l * 8];
#pragma unroll
        for (int sr = 0; sr < 2; sr++)
#pragma unroll
            for (int sc = 0; sc < 4; sc++)
                oacc[sr][sc] = mfma16(afr[sr], bfr[sc], oacc[sr][sc]);
    }
#pragma unroll
    for (int sr = 0; sr < 2; sr++)
#pragma unroll
        for (int sc = 0; sc < 4; sc++) {
            int row = w * 32 + sr * 16;
#pragma unroll
            for (int r = 0; r < 4; r++)
                ps[(row + quad * 4 + r) * QS + sc * 16 + l16] = f2bf(oacc[sr][sc][r]);
        }
    __syncthreads();
#pragma unroll
    for (int i = 0; i < 4; i++) {
        int idx = t + 256 * i, nt = idx >> 7, kcs = (idx >> 6) & 1, lane = idx & 63;
        bf8 v = *(const bf8*)&ps[(nt * 16 + (lane & 15)) * QS + kcs * 32 + (lane >> 4) * 8];
        *(bf8*)&ob[((size_t)((nt0 + nt) * 24 + h * 2 + kcs)) * 512 + lane * 8] = v;
    }
}

// ---------- K6: out = o @ Wp^T + bp  (o frag-linear in, fp32 row-major out) ----------
__global__ __launch_bounds__(256, 3) void k_oproj(const __bf16* __restrict__ ob,
        const __bf16* __restrict__ Wp, const float* __restrict__ bp,
        float* __restrict__ out) {
    int orig = blockIdx.x;
    int lid = (orig & 7) * 192 + (orig >> 3);
    int jt = lid % 6;
    int gt0 = (lid / 6) * 8;
    size_t arow0 = (size_t)(lid / 6) * 128;

    __shared__ __align__(16) __bf16 As3[3 * 4096];  // 24 KB; fp32 epilogue (16 KB/qphase) aliases it
    int t = threadIdx.x, w = t >> 6, l = t & 63, quad = l >> 4, l16 = l & 15;
    int wm = w >> 1, wn = w & 1;
    f4v acc[4][4];
#pragma unroll
    for (int i = 0; i < 4; i++) for (int j = 0; j < 4; j++) acc[i][j] = (f4v)0.0f;

    GEMM_KLOOP_S(ob, Wp);

    // epilogue: 4 quarter-phases (p=wn, hm=wm): single wave dumps 64x64 fp32
    // (pad 68, 16 KB <= 24 KB), all 256 threads store full float4 lines.
    float* ebf = (float*)As3;
    for (int p = 0; p < 2; ++p) {
        for (int hm = 0; hm < 2; ++hm) {
            if (wn == p && wm == hm) {
#pragma unroll
                for (int sc = 0; sc < 4; sc++) {
                    int col = jt * 128 + p * 64 + sc * 16 + l16;
                    float bb = bp[col];
#pragma unroll
                    for (int sr = 0; sr < 4; sr++)
#pragma unroll
                        for (int r = 0; r < 4; r++)
                            ebf[(sr * 16 + quad * 4 + r) * 68 + sc * 16 + l16] = acc[sr][sc][r] + bb;
                }
            }
            __syncthreads();
#pragma unroll
            for (int i = 0; i < 4; i++) {
                int idx = t + 256 * i, row = idx >> 4, c4 = idx & 15;
                *(float4*)&out[(arow0 + hm * 64 + row) * CC + jt * 128 + p * 64 + c4 * 4] =
                    *(const float4*)&ebf[row * 68 + c4 * 4];
            }
            __syncthreads();
        }
    }
}

extern "C" void kernel_launch(void* const* d_in, const int* in_sizes, int n_in,
                              void* d_out, int out_size, void* d_ws, size_t ws_size,
                              hipStream_t stream) {
    (void)in_sizes; (void)n_in; (void)out_size; (void)ws_size;
    const float* x  = (const float*)d_in[0];
    const float* Wc = (const float*)d_in[1];
    const float* bc = (const float*)d_in[2];
    const float* Wq = (const float*)d_in[3];
    const float* bq = (const float*)d_in[4];
    const float* Wk = (const float*)d_in[5];
    const float* bk = (const float*)d_in[6];
    const float* Wv = (const float*)d_in[7];
    const float* bv = (const float*)d_in[8];
    const float* Wp = (const float*)d_in[9];
    const float* bp = (const float*)d_in[10];
    float* out = (float*)d_out;

    char* ws = (char*)d_ws;
    size_t off = 0;
    auto alloc = [&](size_t bytes) { void* p = ws + off; off = (off + bytes + 255) & ~(size_t)255; return p; };
    __bf16* wc_b = (__bf16*)alloc((size_t)MM * CC * 2);
    __bf16* wq_b = (__bf16*)alloc((size_t)CC * CC * 2);
    __bf16* wk_b = (__bf16*)alloc((size_t)CC * CC * 2);
    __bf16* wv_b = (__bf16*)alloc((size_t)CC * CC * 2);
    __bf16* wp_b = (__bf16*)alloc((size_t)CC * CC * 2);
    __bf16* xb   = (__bf16*)alloc((size_t)BB * NN * CC * 2);
    __bf16* xt_o = (__bf16*)alloc((size_t)BB * NN * CC * 2);  // xtf, reused as o (frag)
    __bf16* q_b  = (__bf16*)alloc((size_t)BB * NN * CC * 2);
    __bf16* c_bmn= (__bf16*)alloc((size_t)BB * MM * NN * 2);
    float*  z_f  = (float*) alloc((size_t)BB * MM * CC * 4);
    __bf16* z_b  = (__bf16*)alloc((size_t)BB * MM * CC * 2);
    __bf16* k_b  = (__bf16*)alloc((size_t)BB * HH * MM * DD * 2);
    __bf16* v_t  = (__bf16*)alloc((size_t)BB * HH * MM * DD * 2);

    k_cvtW<<<dim3((CC * CC / 4 + 255) / 256, 5), 256, 0, stream>>>(
        Wc, Wq, Wk, Wv, Wp, wc_b, wq_b, wk_b, wv_b, wp_b);

    k_cvtx<<<dim3(CC / 64, NN / 64, BB), 256, 0, stream>>>(x, xb, xt_o);
    k_cluster<<<dim3(NN / 128, BB), 256, 0, stream>>>(xb, wc_b, bc, c_bmn);
    k_z<<<dim3(CC / 64, BB), 256, 0, stream>>>(c_bmn, xt_o, z_f);
    k_znorm<<<(BB * MM) / 4, 256, 0, stream>>>(z_f, z_b);
    k_kv<<<dim3(CC / 128, BB, 2), 256, 0, stream>>>(z_b, wk_b, bk, wv_b, bv, k_b, v_t);
    k_qproj<<<dim3((BB * NN / 128) * 6), 256, 0, stream>>>(xb, wq_b, bq, q_b);
    k_attn<<<dim3(NN / 128, HH, BB), 256, 0, stream>>>(q_b, k_b, v_t, xt_o /* o reuses xtf */);
    k_oproj<<<dim3((BB * NN / 128) * 6), 256, 0, stream>>>(xt_o, wp_b, bp, out);
}